// Round 1
// baseline (467.417 us; speedup 1.0000x reference)
//
#include <hip/hip_runtime.h>
#include <cstdint>

typedef __attribute__((ext_vector_type(4))) float f32x4;
typedef __attribute__((ext_vector_type(8))) short bf16x8;

#define HIDDEN 2880
#define SEQ 2048
#define QKV_N 5120   // 4096 q + 512 k + 512 v
#define WIN 128

__device__ __forceinline__ ushort f2bf(float f) {
  uint32_t u = __builtin_bit_cast(uint32_t, f);
  u += 0x7fff + ((u >> 16) & 1);
  return (ushort)(u >> 16);
}
__device__ __forceinline__ float bf2f(ushort h) {
  uint32_t u = ((uint32_t)h) << 16;
  return __builtin_bit_cast(float, u);
}

// ---------------- f32 -> bf16 elementwise ----------------
__global__ void conv_kernel(const float* __restrict__ in, ushort* __restrict__ out, int n) {
  int i = (blockIdx.x * blockDim.x + threadIdx.x) * 4;
  if (i >= n) return;
  float4 v = *(const float4*)(in + i);
  ushort4 o;
  o.x = f2bf(v.x); o.y = f2bf(v.y); o.z = f2bf(v.z); o.w = f2bf(v.w);
  *(ushort4*)(out + i) = o;
}

// ---------------- f32 (R x C) -> bf16 transposed (C x R) ----------------
__global__ __launch_bounds__(256) void tconv_kernel(const float* __restrict__ in, ushort* __restrict__ out,
                                                    int R, int C, int out_ld, int out_row_off) {
  __shared__ float tile[32][33];
  int c0 = blockIdx.x * 32, r0 = blockIdx.y * 32;
  int tx = threadIdx.x & 31, ty = threadIdx.x >> 5; // ty 0..7
#pragma unroll
  for (int i = 0; i < 32; i += 8)
    tile[ty + i][tx] = in[(size_t)(r0 + ty + i) * C + c0 + tx];
  __syncthreads();
#pragma unroll
  for (int i = 0; i < 32; i += 8)
    out[(size_t)(out_row_off + c0 + ty + i) * out_ld + r0 + tx] = f2bf(tile[tx][ty + i]);
}

__global__ void zero_kernel(uint4* p, int n) {
  int i = blockIdx.x * blockDim.x + threadIdx.x;
  if (i < n) { uint4 z = {0, 0, 0, 0}; p[i] = z; }
}

__global__ void biascat_kernel(const float* __restrict__ bq, const float* __restrict__ bk,
                               const float* __restrict__ bv, float* __restrict__ out) {
  int i = blockIdx.x * blockDim.x + threadIdx.x;
  if (i >= QKV_N) return;
  float v = (i < 4096) ? bq[i] : (i < 4608) ? bk[i - 4096] : bv[i - 4608];
  out[i] = v;
}

// ---------------- rope cos/sin table: [2048][32] of float2 ----------------
__global__ void ropetab_kernel(float2* __restrict__ tab) {
  int i = blockIdx.x * blockDim.x + threadIdx.x; // 2048*32
  int s = i >> 5, d = i & 31;
  float inv = powf(10000.0f, -(float)d / 32.0f);
  float f = (float)s * inv;
  tab[i] = make_float2(cosf(f), sinf(f));
}

// ---------------- in-place RoPE on a region of qkv ----------------
__global__ void rope_kernel(ushort* __restrict__ buf, const float2* __restrict__ tab, int width, int total) {
  int idx = blockIdx.x * blockDim.x + threadIdx.x;
  if (idx >= total) return;
  int s = idx / width;
  int rr = idx - s * width;
  int d = rr & 63;
  ushort* p = buf + (size_t)s * QKV_N + rr;
  float x = bf2f(*p);
  float partner = __shfl_xor(x, 32, 64);
  float2 cs = tab[(s << 5) + (d & 31)];
  float o = x * cs.x + ((d < 32) ? -partner : partner) * cs.y;
  *p = f2bf(o);
}

// ---------------- bf16 MFMA GEMM: A (MxK row-major), Bt (NxK row-major) ----------------
template <bool OUT_BF16>
__global__ __launch_bounds__(256) void gemm_kernel(
    const ushort* __restrict__ A, const ushort* __restrict__ Bt,
    const float* __restrict__ bias, void* __restrict__ Cv,
    int M, int N, int K, int lda, int ldb, int ldc) {
  __shared__ ushort As[2][128 * 32];
  __shared__ ushort Bs[2][128 * 32];
  const int n0 = blockIdx.x * 128, m0 = blockIdx.y * 128;
  const int tid = threadIdx.x, w = tid >> 6, l = tid & 63;
  const int wm = w >> 1, wn = w & 1;
  const int r = l & 15, g = l >> 4;

  const ushort* Ab = A + (size_t)m0 * lda;
  const ushort* Bb = Bt + (size_t)n0 * ldb;
  const int srow = l >> 2;        // 0..15
  const int scol = (l & 3) * 8;   // 0,8,16,24

  auto stage = [&](int buf, int k0) {
#pragma unroll
    for (int rr2 = 0; rr2 < 2; ++rr2) {
      int chunk = rr2 * 4 + w;  // 0..7
      int row = chunk * 16 + srow;
      const ushort* ga = Ab + (size_t)row * lda + k0 + scol;
      __builtin_amdgcn_global_load_lds((const __attribute__((address_space(1))) void*)(const void*)ga,
                                       (__attribute__((address_space(3))) void*)&As[buf][chunk * 512], 16, 0, 0);
      const ushort* gb = Bb + (size_t)row * ldb + k0 + scol;
      __builtin_amdgcn_global_load_lds((const __attribute__((address_space(1))) void*)(const void*)gb,
                                       (__attribute__((address_space(3))) void*)&Bs[buf][chunk * 512], 16, 0, 0);
    }
  };

  f32x4 acc[4][4] = {};
  const int nk = K / 32;
  stage(0, 0);
  asm volatile("s_waitcnt vmcnt(0)" ::: "memory");
  __syncthreads();
  int buf = 0;
  for (int t = 0; t < nk; ++t) {
    if (t + 1 < nk) stage(buf ^ 1, (t + 1) * 32);
    bf16x8 af[4], bfr[4];
#pragma unroll
    for (int mi = 0; mi < 4; ++mi)
      af[mi] = *(const bf16x8*)&As[buf][(wm * 64 + mi * 16 + r) * 32 + g * 8];
#pragma unroll
    for (int ni = 0; ni < 4; ++ni)
      bfr[ni] = *(const bf16x8*)&Bs[buf][(wn * 64 + ni * 16 + r) * 32 + g * 8];
#pragma unroll
    for (int mi = 0; mi < 4; ++mi)
#pragma unroll
      for (int ni = 0; ni < 4; ++ni)
        acc[mi][ni] = __builtin_amdgcn_mfma_f32_16x16x32_bf16(af[mi], bfr[ni], acc[mi][ni], 0, 0, 0);
    asm volatile("s_waitcnt vmcnt(0)" ::: "memory");
    __syncthreads();
    buf ^= 1;
  }
#pragma unroll
  for (int mi = 0; mi < 4; ++mi) {
#pragma unroll
    for (int ni = 0; ni < 4; ++ni) {
      int cc = n0 + wn * 64 + ni * 16 + r;
      if (cc < N) {
        float b = bias ? bias[cc] : 0.0f;
#pragma unroll
        for (int j = 0; j < 4; ++j) {
          int rr2 = m0 + wm * 64 + mi * 16 + g * 4 + j;
          float v = acc[mi][ni][j] + b;
          if (OUT_BF16) ((ushort*)Cv)[(size_t)rr2 * ldc + cc] = f2bf(v);
          else ((float*)Cv)[(size_t)rr2 * ldc + cc] = v;
        }
      }
    }
  }
}

// ---------------- attention: one wave per (16 q rows, q-head) ----------------
__global__ __launch_bounds__(64) void attn_kernel(
    const ushort* __restrict__ qkv, const float* __restrict__ sinks,
    ushort* __restrict__ out) {
  __shared__ ushort P[16][160];
  __shared__ ushort VT[64][160];
  const int h = blockIdx.y;
  const int q0 = blockIdx.x * 16;
  const int kh = h >> 3;
  const int l = threadIdx.x;
  const int r = l & 15, g = l >> 4;

  {
    uint4 z = {0, 0, 0, 0};
    uint4* pp = (uint4*)&P[0][0];
    for (int i = l; i < 320; i += 64) pp[i] = z;
    uint4* vv = (uint4*)&VT[0][0];
    for (int i = l; i < 1280; i += 64) vv[i] = z;
  }
  __syncthreads();

  const ushort* qb = qkv + (size_t)(q0 + r) * QKV_N + h * 64 + g * 8;
  bf16x8 qf0 = *(const bf16x8*)qb;
  bf16x8 qf1 = *(const bf16x8*)(qb + 32);

  const float scale = 0.125f;
  const int kvbase = q0 - 128;
  f32x4 S[9];
  float mx[4] = {-3e30f, -3e30f, -3e30f, -3e30f};
#pragma unroll
  for (int t = 0; t < 9; ++t) {
    int kv0 = kvbase + t * 16;
    if (kv0 < 0) continue;
    const ushort* kb = qkv + (size_t)(kv0 + r) * QKV_N + 4096 + kh * 64 + g * 8;
    bf16x8 kf0 = *(const bf16x8*)kb;
    bf16x8 kf1 = *(const bf16x8*)(kb + 32);
    f32x4 s = {};
    s = __builtin_amdgcn_mfma_f32_16x16x32_bf16(qf0, kf0, s, 0, 0, 0);
    s = __builtin_amdgcn_mfma_f32_16x16x32_bf16(qf1, kf1, s, 0, 0, 0);
    int kvc = kv0 + r;
#pragma unroll
    for (int j = 0; j < 4; ++j) {
      int qr = q0 + g * 4 + j;
      bool valid = (kvc <= qr) && (kvc >= qr - WIN);
      float v = valid ? s[j] * scale : -1e30f;
      s[j] = v;
      mx[j] = fmaxf(mx[j], v);
    }
    S[t] = s;
  }

  // stage V^T while softmax reductions happen
  for (int kvi = 0; kvi < 144; ++kvi) {
    int kv = kvbase + kvi;
    if (kv < 0) continue;
    VT[l][kvi] = qkv[(size_t)kv * QKV_N + 4608 + kh * 64 + l];
  }

#pragma unroll
  for (int off = 1; off < 16; off <<= 1)
#pragma unroll
    for (int j = 0; j < 4; ++j)
      mx[j] = fmaxf(mx[j], __shfl_xor(mx[j], off, 64));
  float snk = sinks[h];
  float m[4], sum[4] = {0, 0, 0, 0};
#pragma unroll
  for (int j = 0; j < 4; ++j) m[j] = fmaxf(mx[j], snk);
#pragma unroll
  for (int t = 0; t < 9; ++t) {
    int kv0 = kvbase + t * 16;
    if (kv0 < 0) continue;
#pragma unroll
    for (int j = 0; j < 4; ++j) {
      float p = (S[t][j] > -1e29f) ? __expf(S[t][j] - m[j]) : 0.0f;
      S[t][j] = p;
      sum[j] += p;
    }
  }
#pragma unroll
  for (int off = 1; off < 16; off <<= 1)
#pragma unroll
    for (int j = 0; j < 4; ++j)
      sum[j] += __shfl_xor(sum[j], off, 64);
  float rinv[4];
#pragma unroll
  for (int j = 0; j < 4; ++j) rinv[j] = 1.0f / (sum[j] + __expf(snk - m[j]));

#pragma unroll
  for (int t = 0; t < 9; ++t) {
    int kv0 = kvbase + t * 16;
    if (kv0 < 0) continue;
#pragma unroll
    for (int j = 0; j < 4; ++j)
      P[g * 4 + j][t * 16 + r] = f2bf(S[t][j] * rinv[j]);
  }
  __syncthreads();

#pragma unroll
  for (int ni = 0; ni < 4; ++ni) {
    f32x4 acc = {};
#pragma unroll
    for (int ks = 0; ks < 5; ++ks) {
      bf16x8 pa = *(const bf16x8*)&P[r][ks * 32 + g * 8];
      bf16x8 vb = *(const bf16x8*)&VT[ni * 16 + r][ks * 32 + g * 8];
      acc = __builtin_amdgcn_mfma_f32_16x16x32_bf16(pa, vb, acc, 0, 0, 0);
    }
#pragma unroll
    for (int j = 0; j < 4; ++j)
      out[(size_t)(q0 + g * 4 + j) * 4096 + h * 64 + ni * 16 + r] = f2bf(acc[j]);
  }
}

extern "C" void kernel_launch(void* const* d_in, const int* in_sizes, int n_in,
                              void* d_out, int out_size, void* d_ws, size_t ws_size,
                              hipStream_t stream) {
  const float* hs = (const float*)d_in[0];
  const float* Wq = (const float*)d_in[1];
  const float* bq = (const float*)d_in[2];
  const float* Wk = (const float*)d_in[3];
  const float* bk = (const float*)d_in[4];
  const float* Wv = (const float*)d_in[5];
  const float* bv = (const float*)d_in[6];
  const float* Wo = (const float*)d_in[7];
  const float* bo = (const float*)d_in[8];
  const float* sinks = (const float*)d_in[9];
  float* out = (float*)d_out;

  char* ws = (char*)d_ws;
  ushort* hs_bf   = (ushort*)(ws + 0);            // 2048x2880       11,796,480 B
  ushort* wqkv_t  = (ushort*)(ws + 11796480);     // 5120x2880       29,491,200 B
  ushort* wo_t    = (ushort*)(ws + 41287680);     // 2944x4096       24,117,248 B
  ushort* qkv     = (ushort*)(ws + 65404928);     // 2048x5120       20,971,520 B
  ushort* attn    = (ushort*)(ws + 86376448);     // 2048x4096       16,777,216 B
  float*  bias_all= (float*)(ws + 103153664);     // 5120 f32
  float2* tab     = (float2*)(ws + 103174144);    // 2048x32 float2

  // prep: conversions / transposes / tables
  conv_kernel<<<5898240 / 4 / 256, 256, 0, stream>>>(hs, hs_bf, 5898240);
  tconv_kernel<<<dim3(4096 / 32, 2880 / 32), 256, 0, stream>>>(Wq, wqkv_t, 2880, 4096, 2880, 0);
  tconv_kernel<<<dim3(512 / 32, 2880 / 32), 256, 0, stream>>>(Wk, wqkv_t, 2880, 512, 2880, 4096);
  tconv_kernel<<<dim3(512 / 32, 2880 / 32), 256, 0, stream>>>(Wv, wqkv_t, 2880, 512, 2880, 4608);
  tconv_kernel<<<dim3(2880 / 32, 4096 / 32), 256, 0, stream>>>(Wo, wo_t, 4096, 2880, 4096, 0);
  zero_kernel<<<128, 256, 0, stream>>>((uint4*)(wo_t + (size_t)2880 * 4096), 64 * 4096 * 2 / 16);
  biascat_kernel<<<20, 256, 0, stream>>>(bq, bk, bv, bias_all);
  ropetab_kernel<<<2048 * 32 / 256, 256, 0, stream>>>(tab);

  // QKV projection (fused): [2048x2880] x [2880x5120] -> qkv (bf16, +bias)
  gemm_kernel<true><<<dim3(40, 16), 256, 0, stream>>>(hs_bf, wqkv_t, bias_all, qkv,
                                                      2048, 5120, 2880, 2880, 2880, 5120);
  // RoPE in-place on Q and K regions
  rope_kernel<<<8388608 / 256, 256, 0, stream>>>(qkv, tab, 4096, 8388608);
  rope_kernel<<<1048576 / 256, 256, 0, stream>>>(qkv + 4096, tab, 512, 1048576);
  // attention
  attn_kernel<<<dim3(128, 64), 64, 0, stream>>>(qkv, sinks, attn);
  // output projection: [2048x4096] x [4096x2880] -> out (f32, +bo)
  gemm_kernel<false><<<dim3(23, 16), 256, 0, stream>>>(attn, wo_t, bo, out,
                                                       2048, 2880, 4096, 4096, 4096, 2880);
}

// Round 2
// 260.186 us; speedup vs baseline: 1.7965x; 1.7965x over previous
//
#include <hip/hip_runtime.h>
#include <cstdint>

typedef __attribute__((ext_vector_type(4))) float f32x4;
typedef __attribute__((ext_vector_type(8))) short bf16x8;

#define HIDDEN 2880
#define SEQ 2048
#define QKV_N 5120   // 4096 q + 512 k + 512 v
#define WIN 128

__device__ __forceinline__ ushort f2bf(float f) {
  uint32_t u = __builtin_bit_cast(uint32_t, f);
  u += 0x7fff + ((u >> 16) & 1);
  return (ushort)(u >> 16);
}
__device__ __forceinline__ float bf2f(ushort h) {
  uint32_t u = ((uint32_t)h) << 16;
  return __builtin_bit_cast(float, u);
}

// ---------------- f32 -> bf16 elementwise ----------------
__global__ void conv_kernel(const float* __restrict__ in, ushort* __restrict__ out, int n) {
  int i = (blockIdx.x * blockDim.x + threadIdx.x) * 4;
  if (i >= n) return;
  float4 v = *(const float4*)(in + i);
  ushort4 o;
  o.x = f2bf(v.x); o.y = f2bf(v.y); o.z = f2bf(v.z); o.w = f2bf(v.w);
  *(ushort4*)(out + i) = o;
}

// ---------------- f32 (R x C) -> bf16 transposed (C x R) ----------------
__global__ __launch_bounds__(256) void tconv_kernel(const float* __restrict__ in, ushort* __restrict__ out,
                                                    int R, int C, int out_ld, int out_row_off) {
  __shared__ float tile[32][33];
  int c0 = blockIdx.x * 32, r0 = blockIdx.y * 32;
  int tx = threadIdx.x & 31, ty = threadIdx.x >> 5; // ty 0..7
#pragma unroll
  for (int i = 0; i < 32; i += 8)
    tile[ty + i][tx] = in[(size_t)(r0 + ty + i) * C + c0 + tx];
  __syncthreads();
#pragma unroll
  for (int i = 0; i < 32; i += 8)
    out[(size_t)(out_row_off + c0 + ty + i) * out_ld + r0 + tx] = f2bf(tile[tx][ty + i]);
}

__global__ void zero_kernel(uint4* p, int n) {
  int i = blockIdx.x * blockDim.x + threadIdx.x;
  if (i < n) { uint4 z = {0, 0, 0, 0}; p[i] = z; }
}

__global__ void biascat_kernel(const float* __restrict__ bq, const float* __restrict__ bk,
                               const float* __restrict__ bv, float* __restrict__ out) {
  int i = blockIdx.x * blockDim.x + threadIdx.x;
  if (i >= QKV_N) return;
  float v = (i < 4096) ? bq[i] : (i < 4608) ? bk[i - 4096] : bv[i - 4608];
  out[i] = v;
}

// ---------------- rope cos/sin table: [2048][32] of float2 ----------------
__global__ void ropetab_kernel(float2* __restrict__ tab) {
  int i = blockIdx.x * blockDim.x + threadIdx.x; // 2048*32
  int s = i >> 5, d = i & 31;
  float inv = powf(10000.0f, -(float)d / 32.0f);
  float f = (float)s * inv;
  tab[i] = make_float2(cosf(f), sinf(f));
}

// ---------------- in-place RoPE on a region of qkv ----------------
__global__ void rope_kernel(ushort* __restrict__ buf, const float2* __restrict__ tab, int width, int total) {
  int idx = blockIdx.x * blockDim.x + threadIdx.x;
  if (idx >= total) return;
  int s = idx / width;
  int rr = idx - s * width;
  int d = rr & 63;
  ushort* p = buf + (size_t)s * QKV_N + rr;
  float x = bf2f(*p);
  float partner = __shfl_xor(x, 32, 64);
  float2 cs = tab[(s << 5) + (d & 31)];
  float o = x * cs.x + ((d < 32) ? -partner : partner) * cs.y;
  *p = f2bf(o);
}

// ---------------- V transpose: qkv V region [2048][512] -> vt [512][2048] ----------------
__global__ __launch_bounds__(256) void vt_kernel(const ushort* __restrict__ qkv, ushort* __restrict__ vt) {
  __shared__ ushort tile[64][80];
  int kv0 = blockIdx.x * 64, d0 = blockIdx.y * 64;
  int t = threadIdx.x;
#pragma unroll
  for (int p = 0; p < 2; ++p) {
    int lr = p * 32 + (t >> 3);
    *(bf16x8*)&tile[lr][(t & 7) * 8] =
        *(const bf16x8*)&qkv[(size_t)(kv0 + lr) * QKV_N + 4608 + d0 + (t & 7) * 8];
  }
  __syncthreads();
#pragma unroll
  for (int p = 0; p < 2; ++p) {
    int dl = p * 32 + (t >> 3);
    bf16x8 o;
#pragma unroll
    for (int jj = 0; jj < 8; ++jj) o[jj] = (short)tile[(t & 7) * 8 + jj][dl];
    *(bf16x8*)&vt[(size_t)(d0 + dl) * 2048 + kv0 + (t & 7) * 8] = o;
  }
}

// ---------------- bf16 MFMA GEMM: A (MxK row-major), Bt (NxK row-major) ----------------
template <bool OUT_BF16>
__global__ __launch_bounds__(256) void gemm_kernel(
    const ushort* __restrict__ A, const ushort* __restrict__ Bt,
    const float* __restrict__ bias, void* __restrict__ Cv,
    int M, int N, int K, int lda, int ldb, int ldc) {
  __shared__ ushort As[2][128 * 32];
  __shared__ ushort Bs[2][128 * 32];
  const int n0 = blockIdx.x * 128, m0 = blockIdx.y * 128;
  const int tid = threadIdx.x, w = tid >> 6, l = tid & 63;
  const int wm = w >> 1, wn = w & 1;
  const int r = l & 15, g = l >> 4;

  const ushort* Ab = A + (size_t)m0 * lda;
  const ushort* Bb = Bt + (size_t)n0 * ldb;
  const int srow = l >> 2;        // 0..15
  const int scol = (l & 3) * 8;   // 0,8,16,24

  auto stage = [&](int buf, int k0) {
#pragma unroll
    for (int rr2 = 0; rr2 < 2; ++rr2) {
      int chunk = rr2 * 4 + w;  // 0..7
      int row = chunk * 16 + srow;
      const ushort* ga = Ab + (size_t)row * lda + k0 + scol;
      __builtin_amdgcn_global_load_lds((const __attribute__((address_space(1))) void*)(const void*)ga,
                                       (__attribute__((address_space(3))) void*)&As[buf][chunk * 512], 16, 0, 0);
      const ushort* gb = Bb + (size_t)row * ldb + k0 + scol;
      __builtin_amdgcn_global_load_lds((const __attribute__((address_space(1))) void*)(const void*)gb,
                                       (__attribute__((address_space(3))) void*)&Bs[buf][chunk * 512], 16, 0, 0);
    }
  };

  f32x4 acc[4][4] = {};
  const int nk = K / 32;
  stage(0, 0);
  asm volatile("s_waitcnt vmcnt(0)" ::: "memory");
  __syncthreads();
  int buf = 0;
  for (int t = 0; t < nk; ++t) {
    if (t + 1 < nk) stage(buf ^ 1, (t + 1) * 32);
    bf16x8 af[4], bfr[4];
#pragma unroll
    for (int mi = 0; mi < 4; ++mi)
      af[mi] = *(const bf16x8*)&As[buf][(wm * 64 + mi * 16 + r) * 32 + g * 8];
#pragma unroll
    for (int ni = 0; ni < 4; ++ni)
      bfr[ni] = *(const bf16x8*)&Bs[buf][(wn * 64 + ni * 16 + r) * 32 + g * 8];
#pragma unroll
    for (int mi = 0; mi < 4; ++mi)
#pragma unroll
      for (int ni = 0; ni < 4; ++ni)
        acc[mi][ni] = __builtin_amdgcn_mfma_f32_16x16x32_bf16(af[mi], bfr[ni], acc[mi][ni], 0, 0, 0);
    asm volatile("s_waitcnt vmcnt(0)" ::: "memory");
    __syncthreads();
    buf ^= 1;
  }
#pragma unroll
  for (int mi = 0; mi < 4; ++mi) {
#pragma unroll
    for (int ni = 0; ni < 4; ++ni) {
      int cc = n0 + wn * 64 + ni * 16 + r;
      if (cc < N) {
        float b = bias ? bias[cc] : 0.0f;
#pragma unroll
        for (int j = 0; j < 4; ++j) {
          int rr3 = m0 + wm * 64 + mi * 16 + g * 4 + j;
          float v = acc[mi][ni][j] + b;
          if (OUT_BF16) ((ushort*)Cv)[(size_t)rr3 * ldc + cc] = f2bf(v);
          else ((float*)Cv)[(size_t)rr3 * ldc + cc] = v;
        }
      }
    }
  }
}

// ---------------- attention: block = (32 q rows) x (kv head); 8 waves = 8 q heads ----------------
// LDS layout (bytes):
//   Ks: [0, 20480)        160 kv rows x 64 dims bf16, row stride 128B, swizzle byte^=((row&7)<<4)
//   VT: [20480, 40960)    64 dim rows x 160 kv bf16, row stride 320B, swizzle byte^=((row&7)<<4)
//   pad:[40960, 41984)    zeroed (catches ks=4 OOB fragment reads)
//   P:  [41984, 54272)    per-wave [16][48] bf16 chunk buffers (1536B each)
__global__ __launch_bounds__(512, 4) void attn_kernel(
    const ushort* __restrict__ qkv, const ushort* __restrict__ vt,
    const float* __restrict__ sinks, ushort* __restrict__ out) {
  __shared__ __align__(16) char lds[54272];
  const int kh = blockIdx.y;
  const int q0 = blockIdx.x * 32;
  const int kvw0 = q0 - 128;
  const int tid = threadIdx.x, w = tid >> 6, l = tid & 63;
  const int r = l & 15, g = l >> 4;
  const int h = kh * 8 + w;

  if (tid < 256) ((uint32_t*)(lds + 40960))[tid] = 0;

  // stage K (160 rows x 8 x 16B) and VT (64 rows x 20 x 16B): 1280 chunks each
#pragma unroll
  for (int it = 0; it < 3; ++it) {
    int c = it * 512 + tid;
    if (c < 1280) {
      {  // K
        int row = c >> 3, ch = c & 7;
        int kv = kvw0 + row;
        bf16x8 vv = {};
        if (kv >= 0) vv = *(const bf16x8*)&qkv[(size_t)kv * QKV_N + 4096 + kh * 64 + ch * 8];
        int byte = (row * 128 + ch * 16) ^ ((row & 7) << 4);
        *(bf16x8*)(lds + byte) = vv;
      }
      {  // VT
        int row = c / 20, ch = c - (c / 20) * 20;
        int kv = kvw0 + ch * 8;
        bf16x8 vv = {};
        if (kv >= 0) vv = *(const bf16x8*)&vt[(size_t)(kh * 64 + row) * 2048 + kv];
        int byte = (row * 320 + ch * 16) ^ ((row & 7) << 4);
        *(bf16x8*)(lds + 20480 + byte) = vv;
      }
    }
  }
  __syncthreads();

  char* Pw = lds + 41984 + w * 1536;
  const float snk = sinks[h];

#pragma unroll
  for (int si = 0; si < 2; ++si) {
    const ushort* qb = &qkv[(size_t)(q0 + si * 16 + r) * QKV_N + h * 64 + g * 8];
    bf16x8 qf0 = *(const bf16x8*)qb;
    bf16x8 qf1 = *(const bf16x8*)(qb + 32);

    f32x4 S[9];
    float mx[4] = {-3e30f, -3e30f, -3e30f, -3e30f};
#pragma unroll
    for (int tt = 0; tt < 9; ++tt) {
      int kvloc = (si + tt) * 16 + r;
      int b0 = (kvloc * 128 + g * 16) ^ ((kvloc & 7) << 4);
      int b1 = (kvloc * 128 + 64 + g * 16) ^ ((kvloc & 7) << 4);
      bf16x8 kf0 = *(const bf16x8*)(lds + b0);
      bf16x8 kf1 = *(const bf16x8*)(lds + b1);
      f32x4 s = {};
      s = __builtin_amdgcn_mfma_f32_16x16x32_bf16(qf0, kf0, s, 0, 0, 0);
      s = __builtin_amdgcn_mfma_f32_16x16x32_bf16(qf1, kf1, s, 0, 0, 0);
      int kvc = kvw0 + kvloc;
#pragma unroll
      for (int j = 0; j < 4; ++j) {
        int qr = q0 + si * 16 + g * 4 + j;
        bool valid = (kvc >= 0) && (kvc <= qr) && (kvc >= qr - WIN);
        float v = valid ? s[j] * 0.125f : -1e30f;
        s[j] = v;
        mx[j] = fmaxf(mx[j], v);
      }
      S[tt] = s;
    }
#pragma unroll
    for (int off = 1; off < 16; off <<= 1)
#pragma unroll
      for (int j = 0; j < 4; ++j) mx[j] = fmaxf(mx[j], __shfl_xor(mx[j], off, 64));
    float m[4], sum[4] = {0, 0, 0, 0};
#pragma unroll
    for (int j = 0; j < 4; ++j) m[j] = fmaxf(mx[j], snk);
#pragma unroll
    for (int tt = 0; tt < 9; ++tt)
#pragma unroll
      for (int j = 0; j < 4; ++j) {
        float p = (S[tt][j] > -1e29f) ? __expf(S[tt][j] - m[j]) : 0.0f;
        S[tt][j] = p;
        sum[j] += p;
      }
#pragma unroll
    for (int off = 1; off < 16; off <<= 1)
#pragma unroll
      for (int j = 0; j < 4; ++j) sum[j] += __shfl_xor(sum[j], off, 64);
    float rinv[4];
#pragma unroll
    for (int j = 0; j < 4; ++j) rinv[j] = 1.0f / (sum[j] + __expf(snk - m[j]));

    f32x4 acc[4] = {};
#pragma unroll
    for (int ks = 0; ks < 5; ++ks) {
      // write P chunk (window cols ks*32 .. +31); tile 9 does not exist -> zeros
#pragma unroll
      for (int c2 = 0; c2 < 2; ++c2) {
        int tt = 2 * ks + c2;
#pragma unroll
        for (int j = 0; j < 4; ++j) {
          float pv = (tt <= 8) ? S[tt][j] * rinv[j] : 0.0f;
          *(ushort*)(Pw + ((g * 4 + j) * 48 + c2 * 16 + r) * 2) = f2bf(pv);
        }
      }
      bf16x8 pa = *(const bf16x8*)(Pw + (r * 48 + g * 8) * 2);
#pragma unroll
      for (int ni = 0; ni < 4; ++ni) {
        int row = ni * 16 + r;
        int byte = (row * 320 + (si * 16 + ks * 32 + g * 8) * 2) ^ ((row & 7) << 4);
        bf16x8 vb = *(const bf16x8*)(lds + 20480 + byte);
        acc[ni] = __builtin_amdgcn_mfma_f32_16x16x32_bf16(pa, vb, acc[ni], 0, 0, 0);
      }
    }
#pragma unroll
    for (int ni = 0; ni < 4; ++ni)
#pragma unroll
      for (int j = 0; j < 4; ++j)
        out[(size_t)(q0 + si * 16 + g * 4 + j) * 4096 + h * 64 + ni * 16 + r] = f2bf(acc[ni][j]);
  }
}

extern "C" void kernel_launch(void* const* d_in, const int* in_sizes, int n_in,
                              void* d_out, int out_size, void* d_ws, size_t ws_size,
                              hipStream_t stream) {
  const float* hs = (const float*)d_in[0];
  const float* Wq = (const float*)d_in[1];
  const float* bq = (const float*)d_in[2];
  const float* Wk = (const float*)d_in[3];
  const float* bk = (const float*)d_in[4];
  const float* Wv = (const float*)d_in[5];
  const float* bv = (const float*)d_in[6];
  const float* Wo = (const float*)d_in[7];
  const float* bo = (const float*)d_in[8];
  const float* sinks = (const float*)d_in[9];
  float* out = (float*)d_out;

  char* ws = (char*)d_ws;
  ushort* hs_bf   = (ushort*)(ws + 0);            // 2048x2880       11,796,480 B
  ushort* vt_g    = (ushort*)(ws + 0);            // 512x2048 bf16 (reuses hs_bf region after QKV GEMM)
  ushort* wqkv_t  = (ushort*)(ws + 11796480);     // 5120x2880       29,491,200 B
  ushort* wo_t    = (ushort*)(ws + 41287680);     // 2944x4096       24,117,248 B
  ushort* qkv     = (ushort*)(ws + 65404928);     // 2048x5120       20,971,520 B
  ushort* attn    = (ushort*)(ws + 86376448);     // 2048x4096       16,777,216 B
  float*  bias_all= (float*)(ws + 103153664);     // 5120 f32
  float2* tab     = (float2*)(ws + 103174144);    // 2048x32 float2

  // prep: conversions / transposes / tables
  conv_kernel<<<5898240 / 4 / 256, 256, 0, stream>>>(hs, hs_bf, 5898240);
  tconv_kernel<<<dim3(4096 / 32, 2880 / 32), 256, 0, stream>>>(Wq, wqkv_t, 2880, 4096, 2880, 0);
  tconv_kernel<<<dim3(512 / 32, 2880 / 32), 256, 0, stream>>>(Wk, wqkv_t, 2880, 512, 2880, 4096);
  tconv_kernel<<<dim3(512 / 32, 2880 / 32), 256, 0, stream>>>(Wv, wqkv_t, 2880, 512, 2880, 4608);
  tconv_kernel<<<dim3(2880 / 32, 4096 / 32), 256, 0, stream>>>(Wo, wo_t, 4096, 2880, 4096, 0);
  zero_kernel<<<128, 256, 0, stream>>>((uint4*)(wo_t + (size_t)2880 * 4096), 64 * 4096 * 2 / 16);
  biascat_kernel<<<20, 256, 0, stream>>>(bq, bk, bv, bias_all);
  ropetab_kernel<<<2048 * 32 / 256, 256, 0, stream>>>(tab);

  // QKV projection (fused): [2048x2880] x [2880x5120] -> qkv (bf16, +bias)
  gemm_kernel<true><<<dim3(40, 16), 256, 0, stream>>>(hs_bf, wqkv_t, bias_all, qkv,
                                                      2048, 5120, 2880, 2880, 2880, 5120);
  // RoPE in-place on Q and K regions
  rope_kernel<<<8388608 / 256, 256, 0, stream>>>(qkv, tab, 4096, 8388608);
  rope_kernel<<<1048576 / 256, 256, 0, stream>>>(qkv + 4096, tab, 512, 1048576);
  // V transpose (reuses hs_bf scratch; hs_bf is dead after the QKV GEMM)
  vt_kernel<<<dim3(32, 8), 256, 0, stream>>>(qkv, vt_g);
  // attention
  attn_kernel<<<dim3(64, 8), 512, 0, stream>>>(qkv, vt_g, sinks, attn);
  // output projection: [2048x4096] x [4096x2880] -> out (f32, +bo)
  gemm_kernel<false><<<dim3(23, 16), 256, 0, stream>>>(attn, wo_t, bo, out,
                                                       2048, 2880, 4096, 4096, 4096, 2880);
}

// Round 3
// 252.448 us; speedup vs baseline: 1.8515x; 1.0307x over previous
//
#include <hip/hip_runtime.h>
#include <cstdint>

typedef __attribute__((ext_vector_type(4))) float f32x4;
typedef __attribute__((ext_vector_type(8))) short bf16x8;

#define HIDDEN 2880
#define SEQ 2048
#define QKV_N 5120   // 4096 q + 512 k + 512 v
#define WIN 128

__device__ __forceinline__ ushort f2bf(float f) {
  uint32_t u = __builtin_bit_cast(uint32_t, f);
  u += 0x7fff + ((u >> 16) & 1);
  return (ushort)(u >> 16);
}
__device__ __forceinline__ float bf2f(ushort h) {
  uint32_t u = ((uint32_t)h) << 16;
  return __builtin_bit_cast(float, u);
}

// ---------------- f32 -> bf16 elementwise ----------------
__global__ void conv_kernel(const float* __restrict__ in, ushort* __restrict__ out, int n) {
  int i = (blockIdx.x * blockDim.x + threadIdx.x) * 4;
  if (i >= n) return;
  float4 v = *(const float4*)(in + i);
  ushort4 o;
  o.x = f2bf(v.x); o.y = f2bf(v.y); o.z = f2bf(v.z); o.w = f2bf(v.w);
  *(ushort4*)(out + i) = o;
}

// ---------------- f32 (R x C) -> bf16 transposed (C x R) ----------------
__global__ __launch_bounds__(256) void tconv_kernel(const float* __restrict__ in, ushort* __restrict__ out,
                                                    int R, int C, int out_ld, int out_row_off) {
  __shared__ float tile[32][33];
  int c0 = blockIdx.x * 32, r0 = blockIdx.y * 32;
  int tx = threadIdx.x & 31, ty = threadIdx.x >> 5; // ty 0..7
#pragma unroll
  for (int i = 0; i < 32; i += 8)
    tile[ty + i][tx] = in[(size_t)(r0 + ty + i) * C + c0 + tx];
  __syncthreads();
#pragma unroll
  for (int i = 0; i < 32; i += 8)
    out[(size_t)(out_row_off + c0 + ty + i) * out_ld + r0 + tx] = f2bf(tile[tx][ty + i]);
}

__global__ void zero_kernel(uint4* p, int n) {
  int i = blockIdx.x * blockDim.x + threadIdx.x;
  if (i < n) { uint4 z = {0, 0, 0, 0}; p[i] = z; }
}

__global__ void biascat_kernel(const float* __restrict__ bq, const float* __restrict__ bk,
                               const float* __restrict__ bv, float* __restrict__ out) {
  int i = blockIdx.x * blockDim.x + threadIdx.x;
  if (i >= QKV_N) return;
  float v = (i < 4096) ? bq[i] : (i < 4608) ? bk[i - 4096] : bv[i - 4608];
  out[i] = v;
}

// ---------------- rope cos/sin table: [2048][32] of float2 ----------------
__global__ void ropetab_kernel(float2* __restrict__ tab) {
  int i = blockIdx.x * blockDim.x + threadIdx.x; // 2048*32
  int s = i >> 5, d = i & 31;
  float inv = powf(10000.0f, -(float)d / 32.0f);
  float f = (float)s * inv;
  tab[i] = make_float2(cosf(f), sinf(f));
}

// ---------------- in-place RoPE on a region of qkv ----------------
__global__ void rope_kernel(ushort* __restrict__ buf, const float2* __restrict__ tab, int width, int total) {
  int idx = blockIdx.x * blockDim.x + threadIdx.x;
  if (idx >= total) return;
  int s = idx / width;
  int rr = idx - s * width;
  int d = rr & 63;
  ushort* p = buf + (size_t)s * QKV_N + rr;
  float x = bf2f(*p);
  float partner = __shfl_xor(x, 32, 64);
  float2 cs = tab[(s << 5) + (d & 31)];
  float o = x * cs.x + ((d < 32) ? -partner : partner) * cs.y;
  *p = f2bf(o);
}

// ---------------- V transpose: qkv V region [2048][512] -> vt [512][2048] ----------------
__global__ __launch_bounds__(256) void vt_kernel(const ushort* __restrict__ qkv, ushort* __restrict__ vt) {
  __shared__ ushort tile[64][80];
  int kv0 = blockIdx.x * 64, d0 = blockIdx.y * 64;
  int t = threadIdx.x;
#pragma unroll
  for (int p = 0; p < 2; ++p) {
    int lr = p * 32 + (t >> 3);
    *(bf16x8*)&tile[lr][(t & 7) * 8] =
        *(const bf16x8*)&qkv[(size_t)(kv0 + lr) * QKV_N + 4608 + d0 + (t & 7) * 8];
  }
  __syncthreads();
#pragma unroll
  for (int p = 0; p < 2; ++p) {
    int dl = p * 32 + (t >> 3);
    bf16x8 o;
#pragma unroll
    for (int jj = 0; jj < 8; ++jj) o[jj] = (short)tile[(t & 7) * 8 + jj][dl];
    *(bf16x8*)&vt[(size_t)(d0 + dl) * 2048 + kv0 + (t & 7) * 8] = o;
  }
}

// ===================================================================================
// 8-phase MFMA GEMM (T1+T3+T4+T5): A (MxK row-major bf16), Bt (Nx K row-major bf16)
// Tile BM x 256, BK=64 split as two K=32 halves per operand. 8 waves (2M x 4N).
// LDS per buffer: [Ak0 | Ak1 | Bk0 | Bk1], k-half row stride 64B (conflict-free).
// ===================================================================================
template <int BM, bool OUT_BF16, bool NGUARD>
__global__ __launch_bounds__(512, 2) void gemm8_kernel(
    const ushort* __restrict__ A, const ushort* __restrict__ Bt,
    const float* __restrict__ bias, void* __restrict__ Cv,
    int M, int N, int K, int lda, int ldb, int ldc, int nt_n) {
  constexpr int MH = BM / 2;        // rows per wave-m
  constexpr int MFR = BM / 32;      // m-frags per wave (8 / 4)
  constexpr int HM = MFR / 2;       // m-frags per phase (4 / 2)
  constexpr int ABYTES = BM * 64;   // bytes per A k-half
  constexpr int BUFBYTES = 2 * ABYTES + 32768;
  constexpr int ALOADS = BM / 128;  // global_load_lds per A k-half
  __shared__ __align__(16) char ldsbuf[2 * BUFBYTES];

  // XCD-aware swizzle (grid % 8 == 0): XCD x gets a contiguous wg chunk
  const int cpx = gridDim.x >> 3;
  const int wg = ((int)blockIdx.x & 7) * cpx + ((int)blockIdx.x >> 3);
  const int mtile = wg / nt_n, ntile = wg - mtile * nt_n;
  const int m0 = mtile * BM, n0 = ntile * 256;

  const int tid = threadIdx.x, wv = tid >> 6, l = tid & 63;
  const int wm = wv >> 2, wn = wv & 3;
  const int r = l & 15, g = l >> 4;

  const ushort* gA0 = A + (size_t)(m0 + wv * 16 + (l >> 2)) * lda + (l & 3) * 8;
  const ushort* gB0 = Bt + (size_t)(n0 + wv * 16 + (l >> 2)) * ldb + (l & 3) * 8;
  const int aOff = (wm * MH + r) * 64 + g * 16;
  const int bOff = (wn * 64 + r) * 64 + g * 16;

  auto sA = [&](int nb, int kg, int kh) {
#pragma unroll
    for (int i = 0; i < ALOADS; ++i)
      __builtin_amdgcn_global_load_lds(
          (const __attribute__((address_space(1))) void*)(const void*)(gA0 + (size_t)i * 128 * lda + kg),
          (__attribute__((address_space(3))) void*)&ldsbuf[nb * BUFBYTES + kh * ABYTES + i * 8192 + wv * 1024],
          16, 0, 0);
  };
  auto sB = [&](int nb, int kg, int kh) {
#pragma unroll
    for (int i = 0; i < 2; ++i)
      __builtin_amdgcn_global_load_lds(
          (const __attribute__((address_space(1))) void*)(const void*)(gB0 + (size_t)i * 128 * ldb + kg),
          (__attribute__((address_space(3))) void*)&ldsbuf[nb * BUFBYTES + 2 * ABYTES + kh * 16384 + i * 8192 + wv * 1024],
          16, 0, 0);
  };

#define BAR() __builtin_amdgcn_s_barrier()
#define LGKM0()                                              \
  do {                                                       \
    asm volatile("s_waitcnt lgkmcnt(0)" ::: "memory");       \
    __builtin_amdgcn_sched_barrier(0);                       \
  } while (0)
#define WAITVN()                                                          \
  do {                                                                    \
    if constexpr (BM == 256) asm volatile("s_waitcnt vmcnt(4)" ::: "memory"); \
    else asm volatile("s_waitcnt vmcnt(3)" ::: "memory");                 \
  } while (0)
#define WAITV0() asm volatile("s_waitcnt vmcnt(0)" ::: "memory")
#define READ_A(KH, MF0)                                                           \
  _Pragma("unroll") for (int i2 = 0; i2 < HM; ++i2)                               \
      aq[i2] = *(const bf16x8*)&ldsbuf[bufOff + (KH)*ABYTES + aOff + ((MF0) + i2) * 1024];
#define READ_B(KH)                                                                \
  _Pragma("unroll") for (int nf = 0; nf < 4; ++nf)                                \
      bq[nf] = *(const bf16x8*)&ldsbuf[bufOff + 2 * ABYTES + (KH)*16384 + bOff + nf * 1024];
#define PHASE_MFMA(MB)                                                            \
  __builtin_amdgcn_s_setprio(1);                                                  \
  _Pragma("unroll") for (int i2 = 0; i2 < HM; ++i2) {                             \
    _Pragma("unroll") for (int nf = 0; nf < 4; ++nf)                              \
        acc[(MB) + i2][nf] = __builtin_amdgcn_mfma_f32_16x16x32_bf16(             \
            aq[i2], bq[nf], acc[(MB) + i2][nf], 0, 0, 0);                         \
  }                                                                               \
  __builtin_amdgcn_s_setprio(0)

  f32x4 acc[MFR][4] = {};

  // prologue: stage tile 0 (order: Ak0,Bk0 first -> they drain at vmcnt(N))
  sA(0, 0, 0); sB(0, 0, 0); sA(0, 32, 1); sB(0, 32, 1);
  WAITVN();
  BAR();

  const int nt = K >> 6;
  for (int t = 0; t < nt; ++t) {
    const int buf = t & 1, nbuf = buf ^ 1;
    const int bufOff = buf * BUFBYTES;
    const int kn = (t + 1) << 6;
    const bool haveNext = (t + 1 < nt);
    bf16x8 aq[HM], bq[4];

    // ---- phase 1: ksub0, m-frags [0,HM) ----
    READ_B(0); READ_A(0, 0);
    if (haveNext) sA(nbuf, kn, 0);
    BAR(); LGKM0();
    PHASE_MFMA(0);
    BAR();
    // ---- phase 2: ksub0, m-frags [HM,MFR) ----
    READ_A(0, HM);
    if (haveNext) { sB(nbuf, kn, 0); WAITVN(); } else { WAITV0(); }
    BAR(); LGKM0();
    PHASE_MFMA(HM);
    BAR();
    // ---- phase 3: ksub1, m-frags [0,HM) ----
    READ_B(1); READ_A(1, 0);
    if (haveNext) sA(nbuf, kn + 32, 1);
    BAR(); LGKM0();
    PHASE_MFMA(0);
    BAR();
    // ---- phase 4: ksub1, m-frags [HM,MFR) ----
    READ_A(1, HM);
    if (haveNext) { sB(nbuf, kn + 32, 1); WAITVN(); } else { WAITV0(); }
    BAR(); LGKM0();
    PHASE_MFMA(HM);
    BAR();
  }

  // epilogue: C write (+bias)
#pragma unroll
  for (int mf2 = 0; mf2 < MFR; ++mf2) {
#pragma unroll
    for (int nf = 0; nf < 4; ++nf) {
      int cc = n0 + wn * 64 + nf * 16 + r;
      if (!NGUARD || cc < N) {
        float b = bias[cc];
#pragma unroll
        for (int j = 0; j < 4; ++j) {
          int rrow = m0 + wm * MH + mf2 * 16 + g * 4 + j;
          float v = acc[mf2][nf][j] + b;
          if (OUT_BF16) ((ushort*)Cv)[(size_t)rrow * ldc + cc] = f2bf(v);
          else ((float*)Cv)[(size_t)rrow * ldc + cc] = v;
        }
      }
    }
  }
#undef BAR
#undef LGKM0
#undef WAITVN
#undef WAITV0
#undef READ_A
#undef READ_B
#undef PHASE_MFMA
}

// ---------------- attention: block = (32 q rows) x (kv head); 8 waves = 8 q heads ----------------
__global__ __launch_bounds__(512, 4) void attn_kernel(
    const ushort* __restrict__ qkv, const ushort* __restrict__ vt,
    const float* __restrict__ sinks, ushort* __restrict__ out) {
  __shared__ __align__(16) char lds[54272];
  const int kh = blockIdx.y;
  const int q0 = blockIdx.x * 32;
  const int kvw0 = q0 - 128;
  const int tid = threadIdx.x, w = tid >> 6, l = tid & 63;
  const int r = l & 15, g = l >> 4;
  const int h = kh * 8 + w;

  if (tid < 256) ((uint32_t*)(lds + 40960))[tid] = 0;

#pragma unroll
  for (int it = 0; it < 3; ++it) {
    int c = it * 512 + tid;
    if (c < 1280) {
      {  // K
        int row = c >> 3, ch = c & 7;
        int kv = kvw0 + row;
        bf16x8 vv = {};
        if (kv >= 0) vv = *(const bf16x8*)&qkv[(size_t)kv * QKV_N + 4096 + kh * 64 + ch * 8];
        int byte = (row * 128 + ch * 16) ^ ((row & 7) << 4);
        *(bf16x8*)(lds + byte) = vv;
      }
      {  // VT
        int row = c / 20, ch = c - (c / 20) * 20;
        int kv = kvw0 + ch * 8;
        bf16x8 vv = {};
        if (kv >= 0) vv = *(const bf16x8*)&vt[(size_t)(kh * 64 + row) * 2048 + kv];
        int byte = (row * 320 + ch * 16) ^ ((row & 7) << 4);
        *(bf16x8*)(lds + 20480 + byte) = vv;
      }
    }
  }
  __syncthreads();

  char* Pw = lds + 41984 + w * 1536;
  const float snk = sinks[h];

#pragma unroll
  for (int si = 0; si < 2; ++si) {
    const ushort* qb = &qkv[(size_t)(q0 + si * 16 + r) * QKV_N + h * 64 + g * 8];
    bf16x8 qf0 = *(const bf16x8*)qb;
    bf16x8 qf1 = *(const bf16x8*)(qb + 32);

    f32x4 S[9];
    float mx[4] = {-3e30f, -3e30f, -3e30f, -3e30f};
#pragma unroll
    for (int tt = 0; tt < 9; ++tt) {
      int kvloc = (si + tt) * 16 + r;
      int b0 = (kvloc * 128 + g * 16) ^ ((kvloc & 7) << 4);
      int b1 = (kvloc * 128 + 64 + g * 16) ^ ((kvloc & 7) << 4);
      bf16x8 kf0 = *(const bf16x8*)(lds + b0);
      bf16x8 kf1 = *(const bf16x8*)(lds + b1);
      f32x4 s = {};
      s = __builtin_amdgcn_mfma_f32_16x16x32_bf16(qf0, kf0, s, 0, 0, 0);
      s = __builtin_amdgcn_mfma_f32_16x16x32_bf16(qf1, kf1, s, 0, 0, 0);
      int kvc = kvw0 + kvloc;
#pragma unroll
      for (int j = 0; j < 4; ++j) {
        int qr = q0 + si * 16 + g * 4 + j;
        bool valid = (kvc >= 0) && (kvc <= qr) && (kvc >= qr - WIN);
        float v = valid ? s[j] * 0.125f : -1e30f;
        s[j] = v;
        mx[j] = fmaxf(mx[j], v);
      }
      S[tt] = s;
    }
#pragma unroll
    for (int off = 1; off < 16; off <<= 1)
#pragma unroll
      for (int j = 0; j < 4; ++j) mx[j] = fmaxf(mx[j], __shfl_xor(mx[j], off, 64));
    float m[4], sum[4] = {0, 0, 0, 0};
#pragma unroll
    for (int j = 0; j < 4; ++j) m[j] = fmaxf(mx[j], snk);
#pragma unroll
    for (int tt = 0; tt < 9; ++tt)
#pragma unroll
      for (int j = 0; j < 4; ++j) {
        float p = (S[tt][j] > -1e29f) ? __expf(S[tt][j] - m[j]) : 0.0f;
        S[tt][j] = p;
        sum[j] += p;
      }
#pragma unroll
    for (int off = 1; off < 16; off <<= 1)
#pragma unroll
      for (int j = 0; j < 4; ++j) sum[j] += __shfl_xor(sum[j], off, 64);
    float rinv[4];
#pragma unroll
    for (int j = 0; j < 4; ++j) rinv[j] = 1.0f / (sum[j] + __expf(snk - m[j]));

    f32x4 acc[4] = {};
#pragma unroll
    for (int ks = 0; ks < 5; ++ks) {
#pragma unroll
      for (int c2 = 0; c2 < 2; ++c2) {
        int tt = 2 * ks + c2;
#pragma unroll
        for (int j = 0; j < 4; ++j) {
          float pv = (tt <= 8) ? S[tt][j] * rinv[j] : 0.0f;
          *(ushort*)(Pw + ((g * 4 + j) * 48 + c2 * 16 + r) * 2) = f2bf(pv);
        }
      }
      bf16x8 pa = *(const bf16x8*)(Pw + (r * 48 + g * 8) * 2);
#pragma unroll
      for (int ni = 0; ni < 4; ++ni) {
        int row = ni * 16 + r;
        int byte = (row * 320 + (si * 16 + ks * 32 + g * 8) * 2) ^ ((row & 7) << 4);
        bf16x8 vb = *(const bf16x8*)(lds + 20480 + byte);
        acc[ni] = __builtin_amdgcn_mfma_f32_16x16x32_bf16(pa, vb, acc[ni], 0, 0, 0);
      }
    }
#pragma unroll
    for (int ni = 0; ni < 4; ++ni)
#pragma unroll
      for (int j = 0; j < 4; ++j)
        out[(size_t)(q0 + si * 16 + g * 4 + j) * 4096 + h * 64 + ni * 16 + r] = f2bf(acc[ni][j]);
  }
}

extern "C" void kernel_launch(void* const* d_in, const int* in_sizes, int n_in,
                              void* d_out, int out_size, void* d_ws, size_t ws_size,
                              hipStream_t stream) {
  const float* hs = (const float*)d_in[0];
  const float* Wq = (const float*)d_in[1];
  const float* bq = (const float*)d_in[2];
  const float* Wk = (const float*)d_in[3];
  const float* bk = (const float*)d_in[4];
  const float* Wv = (const float*)d_in[5];
  const float* bv = (const float*)d_in[6];
  const float* Wo = (const float*)d_in[7];
  const float* bo = (const float*)d_in[8];
  const float* sinks = (const float*)d_in[9];
  float* out = (float*)d_out;

  char* ws = (char*)d_ws;
  ushort* hs_bf   = (ushort*)(ws + 0);            // 2048x2880 bf16      11,796,480 B
  ushort* vt_g    = (ushort*)(ws + 0);            // 512x2048  bf16 (reuses hs_bf after QKV GEMM)
  ushort* wqkv_t  = (ushort*)(ws + 11796480);     // 5120x2880 bf16      29,491,200 B
  ushort* attn    = (ushort*)(ws + 11796480);     // 2048x4096 bf16 (reuses wqkv_t after QKV GEMM)
  ushort* wo_t    = (ushort*)(ws + 41287680);     // 3072x4096 bf16      25,165,824 B (rows 2880+ zero pad)
  ushort* qkv     = (ushort*)(ws + 66453504);     // 2048x5120 bf16      20,971,520 B
  float*  bias_all= (float*)(ws + 87425024);      // 5120 f32
  float2* tab     = (float2*)(ws + 87445504);     // 2048x32 float2

  // prep: conversions / transposes / tables
  conv_kernel<<<5898240 / 4 / 256, 256, 0, stream>>>(hs, hs_bf, 5898240);
  tconv_kernel<<<dim3(4096 / 32, 2880 / 32), 256, 0, stream>>>(Wq, wqkv_t, 2880, 4096, 2880, 0);
  tconv_kernel<<<dim3(512 / 32, 2880 / 32), 256, 0, stream>>>(Wk, wqkv_t, 2880, 512, 2880, 4096);
  tconv_kernel<<<dim3(512 / 32, 2880 / 32), 256, 0, stream>>>(Wv, wqkv_t, 2880, 512, 2880, 4608);
  tconv_kernel<<<dim3(2880 / 32, 4096 / 32), 256, 0, stream>>>(Wo, wo_t, 4096, 2880, 4096, 0);
  zero_kernel<<<384, 256, 0, stream>>>((uint4*)(wo_t + (size_t)2880 * 4096), 98304);
  biascat_kernel<<<20, 256, 0, stream>>>(bq, bk, bv, bias_all);
  ropetab_kernel<<<2048 * 32 / 256, 256, 0, stream>>>(tab);

  // QKV projection (fused): [2048x2880] x [2880x5120] -> qkv (bf16, +bias). 160 wg (8x20)
  gemm8_kernel<256, true, false><<<160, 512, 0, stream>>>(hs_bf, wqkv_t, bias_all, qkv,
                                                          2048, 5120, 2880, 2880, 2880, 5120, 20);
  // RoPE in-place on Q and K regions
  rope_kernel<<<8388608 / 256, 256, 0, stream>>>(qkv, tab, 4096, 8388608);
  rope_kernel<<<1048576 / 256, 256, 0, stream>>>(qkv + 4096, tab, 512, 1048576);
  // V transpose (into dead hs_bf region)
  vt_kernel<<<dim3(32, 8), 256, 0, stream>>>(qkv, vt_g);
  // attention (into dead wqkv_t region)
  attn_kernel<<<dim3(64, 8), 512, 0, stream>>>(qkv, vt_g, sinks, attn);
  // output projection: [2048x4096] x [4096x2880] -> out (f32, +bo). 192 wg (16x12)
  gemm8_kernel<128, false, true><<<192, 512, 0, stream>>>(attn, wo_t, bo, out,
                                                          2048, 2880, 4096, 4096, 4096, 2880, 12);
}

// Round 4
// 214.912 us; speedup vs baseline: 2.1749x; 1.1747x over previous
//
#include <hip/hip_runtime.h>
#include <cstdint>

typedef __attribute__((ext_vector_type(4))) float f32x4;
typedef __attribute__((ext_vector_type(8))) short bf16x8;

#define HIDDEN 2880
#define SEQ 2048
#define QKV_N 5120   // 4096 q + 512 k + 512 v
#define WIN 128

__device__ __forceinline__ ushort f2bf(float f) {
  uint32_t u = __builtin_bit_cast(uint32_t, f);
  u += 0x7fff + ((u >> 16) & 1);
  return (ushort)(u >> 16);
}
__device__ __forceinline__ float bf2f(ushort h) {
  uint32_t u = ((uint32_t)h) << 16;
  return __builtin_bit_cast(float, u);
}

// ---------------- f32 -> bf16 elementwise ----------------
__global__ void conv_kernel(const float* __restrict__ in, ushort* __restrict__ out, int n) {
  int i = (blockIdx.x * blockDim.x + threadIdx.x) * 4;
  if (i >= n) return;
  float4 v = *(const float4*)(in + i);
  ushort4 o;
  o.x = f2bf(v.x); o.y = f2bf(v.y); o.z = f2bf(v.z); o.w = f2bf(v.w);
  *(ushort4*)(out + i) = o;
}

// ---------------- f32 (R x C) -> bf16 transposed (C x R) ----------------
__global__ __launch_bounds__(256) void tconv_kernel(const float* __restrict__ in, ushort* __restrict__ out,
                                                    int R, int C, int out_ld, int out_row_off) {
  __shared__ float tile[32][33];
  int c0 = blockIdx.x * 32, r0 = blockIdx.y * 32;
  int tx = threadIdx.x & 31, ty = threadIdx.x >> 5; // ty 0..7
#pragma unroll
  for (int i = 0; i < 32; i += 8)
    tile[ty + i][tx] = in[(size_t)(r0 + ty + i) * C + c0 + tx];
  __syncthreads();
#pragma unroll
  for (int i = 0; i < 32; i += 8)
    out[(size_t)(out_row_off + c0 + ty + i) * out_ld + r0 + tx] = f2bf(tile[tx][ty + i]);
}

__global__ void biascat_kernel(const float* __restrict__ bq, const float* __restrict__ bk,
                               const float* __restrict__ bv, float* __restrict__ out) {
  int i = blockIdx.x * blockDim.x + threadIdx.x;
  if (i >= QKV_N) return;
  float v = (i < 4096) ? bq[i] : (i < 4608) ? bk[i - 4096] : bv[i - 4608];
  out[i] = v;
}

// ---------------- rope cos/sin table: [2048][32] of float2 ----------------
__global__ void ropetab_kernel(float2* __restrict__ tab) {
  int i = blockIdx.x * blockDim.x + threadIdx.x; // 2048*32
  int s = i >> 5, d = i & 31;
  float inv = powf(10000.0f, -(float)d / 32.0f);
  float f = (float)s * inv;
  tab[i] = make_float2(cosf(f), sinf(f));
}

// ---------------- in-place RoPE on a region of qkv ----------------
__global__ void rope_kernel(ushort* __restrict__ buf, const float2* __restrict__ tab, int width, int total) {
  int idx = blockIdx.x * blockDim.x + threadIdx.x;
  if (idx >= total) return;
  int s = idx / width;
  int rr = idx - s * width;
  int d = rr & 63;
  ushort* p = buf + (size_t)s * QKV_N + rr;
  float x = bf2f(*p);
  float partner = __shfl_xor(x, 32, 64);
  float2 cs = tab[(s << 5) + (d & 31)];
  float o = x * cs.x + ((d < 32) ? -partner : partner) * cs.y;
  *p = f2bf(o);
}

// ---------------- V transpose: qkv V region [2048][512] -> vt [512][2048] ----------------
__global__ __launch_bounds__(256) void vt_kernel(const ushort* __restrict__ qkv, ushort* __restrict__ vt) {
  __shared__ ushort tile[64][80];
  int kv0 = blockIdx.x * 64, d0 = blockIdx.y * 64;
  int t = threadIdx.x;
#pragma unroll
  for (int p = 0; p < 2; ++p) {
    int lr = p * 32 + (t >> 3);
    *(bf16x8*)&tile[lr][(t & 7) * 8] =
        *(const bf16x8*)&qkv[(size_t)(kv0 + lr) * QKV_N + 4608 + d0 + (t & 7) * 8];
  }
  __syncthreads();
#pragma unroll
  for (int p = 0; p < 2; ++p) {
    int dl = p * 32 + (t >> 3);
    bf16x8 o;
#pragma unroll
    for (int jj = 0; jj < 8; ++jj) o[jj] = (short)tile[(t & 7) * 8 + jj][dl];
    *(bf16x8*)&vt[(size_t)(d0 + dl) * 2048 + kv0 + (t & 7) * 8] = o;
  }
}

// ===================================================================================
// 8-phase MFMA GEMM, BM=128 x BN tile, 16 m-tiles. 8 waves as 2m x 4n.
// Grid must be (M/128)*(N/BN), divisible by 8. wg n-major: ntile=wg>>4, mtile=wg&15.
// LDS/buffer: [Ak0|Ak1|Bk0|Bk1]; 64B row stride; XOR swizzle phys^=((log>>7)&3)<<4
// (read side: bit4-5 of addr; stage side: pre-swizzled global source chunk).
// ===================================================================================
template <int BN, bool OUT_BF16>
__global__ __launch_bounds__(512, 2) void gemm8_kernel(
    const ushort* __restrict__ A, const ushort* __restrict__ Bt,
    const float* __restrict__ bias, void* __restrict__ Cv,
    int K, int lda, int ldb, int ldc) {
  constexpr int NFRAG = BN / 64;          // n-frags per wave
  constexpr int BHALF = BN * 64;          // bytes per B k-half
  constexpr int BCHUNKS = BHALF / 1024;   // 1KB issues per B k-half
  constexpr int BJ = BCHUNKS / 8, BR = BCHUNKS & 7;
  constexpr int BUFBYTES = 16384 + 2 * BHALF;
  __shared__ __align__(16) char ldsbuf[2 * BUFBYTES];

  // XCD-aware swizzle (grid % 8 == 0)
  const int cpx = gridDim.x >> 3;
  const int wg = ((int)blockIdx.x & 7) * cpx + ((int)blockIdx.x >> 3);
  const int mtile = wg & 15, ntile = wg >> 4;
  const int m0 = mtile * 128, n0 = ntile * BN;

  const int tid = threadIdx.x, wv = tid >> 6, l = tid & 63;
  const int wm = wv >> 2, wn = wv & 3;
  const int r = l & 15, g = l >> 4;

  // staging source: pre-swizzled chunk (rule 21: linear LDS dest, inv-swz source)
  const int c = l ^ ((l >> 3) & 3);
  const ushort* gA0 = A + (size_t)(m0 + wv * 16 + (c >> 2)) * lda + (c & 3) * 8;
  const ushort* gB0 = Bt + (size_t)(n0 + (c >> 2)) * ldb + (c & 3) * 8;

  // fragment read offsets (swizzle applied to addr bits 4-5)
  const int gsw = (g * 16) ^ (((r >> 1) & 3) << 4);
  const int aOff = (wm * 64 + r) * 64 + gsw;
  const int bOff = (wn * NFRAG * 16 + r) * 64 + gsw;

  auto sA = [&](int nb, int kg, int kh) {
    __builtin_amdgcn_global_load_lds(
        (const __attribute__((address_space(1))) void*)(const void*)(gA0 + kg),
        (__attribute__((address_space(3))) void*)&ldsbuf[nb * BUFBYTES + kh * 8192 + wv * 1024], 16, 0, 0);
  };
  auto sB = [&](int nb, int kg, int kh) {
#pragma unroll
    for (int j = 0; j < (BCHUNKS + 7) / 8; ++j) {
      int cid = j * 8 + wv;
      if (cid < BCHUNKS)
        __builtin_amdgcn_global_load_lds(
            (const __attribute__((address_space(1))) void*)(const void*)(gB0 + (size_t)cid * 16 * ldb + kg),
            (__attribute__((address_space(3))) void*)&ldsbuf[nb * BUFBYTES + 16384 + kh * BHALF + cid * 1024],
            16, 0, 0);
    }
  };

#define BAR() __builtin_amdgcn_s_barrier()
#define LGKM0()                                              \
  do {                                                       \
    asm volatile("s_waitcnt lgkmcnt(0)" ::: "memory");       \
    __builtin_amdgcn_sched_barrier(0);                       \
  } while (0)
#define WAITVN()                                                                   \
  do {                                                                             \
    if (wv < BR) asm volatile("s_waitcnt vmcnt(%0)" ::"n"(BJ + 2) : "memory");     \
    else asm volatile("s_waitcnt vmcnt(%0)" ::"n"(BJ + 1) : "memory");             \
  } while (0)
#define WAITV0() asm volatile("s_waitcnt vmcnt(0)" ::: "memory")
#define READ_A(KH, MF0)                                                            \
  _Pragma("unroll") for (int i2 = 0; i2 < 2; ++i2)                                 \
      aq[i2] = *(const bf16x8*)&ldsbuf[bufOff + (KH)*8192 + aOff + ((MF0) + i2) * 1024];
#define READ_B(KH)                                                                 \
  _Pragma("unroll") for (int nf = 0; nf < NFRAG; ++nf)                             \
      bq[nf] = *(const bf16x8*)&ldsbuf[bufOff + 16384 + (KH)*BHALF + bOff + nf * 1024];
#define PHASE_MFMA(MB)                                                             \
  __builtin_amdgcn_s_setprio(1);                                                   \
  _Pragma("unroll") for (int i2 = 0; i2 < 2; ++i2) {                               \
    _Pragma("unroll") for (int nf = 0; nf < NFRAG; ++nf)                           \
        acc[(MB) + i2][nf] = __builtin_amdgcn_mfma_f32_16x16x32_bf16(              \
            aq[i2], bq[nf], acc[(MB) + i2][nf], 0, 0, 0);                          \
  }                                                                                \
  __builtin_amdgcn_s_setprio(0)

  f32x4 acc[4][NFRAG] = {};

  // prologue: stage tile 0 (Ak0,Bk0 first -> drained by WAITVN; Ak1,Bk1 stay in flight)
  sA(0, 0, 0); sB(0, 0, 0); sA(0, 32, 1); sB(0, 32, 1);
  WAITVN();
  BAR();

  const int nt = K >> 6;
  for (int t = 0; t < nt; ++t) {
    const int buf = t & 1, nbuf = buf ^ 1;
    const int bufOff = buf * BUFBYTES;
    const int kn = (t + 1) << 6;
    const bool haveNext = (t + 1 < nt);
    bf16x8 aq[2], bq[NFRAG];

    // ---- phase 1: ksub0, m-frags 0-1 ----
    READ_B(0); READ_A(0, 0);
    if (haveNext) sA(nbuf, kn, 0);
    BAR(); LGKM0();
    PHASE_MFMA(0);
    BAR();
    // ---- phase 2: ksub0, m-frags 2-3 ----
    READ_A(0, 2);
    if (haveNext) { sB(nbuf, kn, 0); WAITVN(); } else { WAITV0(); }
    BAR(); LGKM0();
    PHASE_MFMA(2);
    BAR();
    // ---- phase 3: ksub1, m-frags 0-1 ----
    READ_B(1); READ_A(1, 0);
    if (haveNext) sA(nbuf, kn + 32, 1);
    BAR(); LGKM0();
    PHASE_MFMA(0);
    BAR();
    // ---- phase 4: ksub1, m-frags 2-3 ----
    READ_A(1, 2);
    if (haveNext) { sB(nbuf, kn + 32, 1); WAITVN(); } else { WAITV0(); }
    BAR(); LGKM0();
    PHASE_MFMA(2);
    BAR();
  }

  // epilogue: C write (+bias); all tile bounds exact, no guards
#pragma unroll
  for (int mf2 = 0; mf2 < 4; ++mf2) {
#pragma unroll
    for (int nf = 0; nf < NFRAG; ++nf) {
      int cc = n0 + wn * (NFRAG * 16) + nf * 16 + r;
      float b = bias[cc];
#pragma unroll
      for (int j = 0; j < 4; ++j) {
        int rrow = m0 + wm * 64 + mf2 * 16 + g * 4 + j;
        float v = acc[mf2][nf][j] + b;
        if (OUT_BF16) ((ushort*)Cv)[(size_t)rrow * ldc + cc] = f2bf(v);
        else ((float*)Cv)[(size_t)rrow * ldc + cc] = v;
      }
    }
  }
#undef BAR
#undef LGKM0
#undef WAITVN
#undef WAITV0
#undef READ_A
#undef READ_B
#undef PHASE_MFMA
}

// ---------------- attention: block = (32 q rows) x (kv head); 8 waves = 8 q heads ----------------
__global__ __launch_bounds__(512, 4) void attn_kernel(
    const ushort* __restrict__ qkv, const ushort* __restrict__ vt,
    const float* __restrict__ sinks, ushort* __restrict__ out) {
  __shared__ __align__(16) char lds[54272];
  const int kh = blockIdx.y;
  const int q0 = blockIdx.x * 32;
  const int kvw0 = q0 - 128;
  const int tid = threadIdx.x, w = tid >> 6, l = tid & 63;
  const int r = l & 15, g = l >> 4;
  const int h = kh * 8 + w;

  if (tid < 256) ((uint32_t*)(lds + 40960))[tid] = 0;

#pragma unroll
  for (int it = 0; it < 3; ++it) {
    int c = it * 512 + tid;
    if (c < 1280) {
      {  // K
        int row = c >> 3, ch = c & 7;
        int kv = kvw0 + row;
        bf16x8 vv = {};
        if (kv >= 0) vv = *(const bf16x8*)&qkv[(size_t)kv * QKV_N + 4096 + kh * 64 + ch * 8];
        int byte = (row * 128 + ch * 16) ^ ((row & 7) << 4);
        *(bf16x8*)(lds + byte) = vv;
      }
      {  // VT
        int row = c / 20, ch = c - (c / 20) * 20;
        int kv = kvw0 + ch * 8;
        bf16x8 vv = {};
        if (kv >= 0) vv = *(const bf16x8*)&vt[(size_t)(kh * 64 + row) * 2048 + kv];
        int byte = (row * 320 + ch * 16) ^ ((row & 7) << 4);
        *(bf16x8*)(lds + 20480 + byte) = vv;
      }
    }
  }
  __syncthreads();

  char* Pw = lds + 41984 + w * 1536;
  const float snk = sinks[h];

#pragma unroll
  for (int si = 0; si < 2; ++si) {
    const ushort* qb = &qkv[(size_t)(q0 + si * 16 + r) * QKV_N + h * 64 + g * 8];
    bf16x8 qf0 = *(const bf16x8*)qb;
    bf16x8 qf1 = *(const bf16x8*)(qb + 32);

    f32x4 S[9];
    float mx[4] = {-3e30f, -3e30f, -3e30f, -3e30f};
#pragma unroll
    for (int tt = 0; tt < 9; ++tt) {
      int kvloc = (si + tt) * 16 + r;
      int b0 = (kvloc * 128 + g * 16) ^ ((kvloc & 7) << 4);
      int b1 = (kvloc * 128 + 64 + g * 16) ^ ((kvloc & 7) << 4);
      bf16x8 kf0 = *(const bf16x8*)(lds + b0);
      bf16x8 kf1 = *(const bf16x8*)(lds + b1);
      f32x4 s = {};
      s = __builtin_amdgcn_mfma_f32_16x16x32_bf16(qf0, kf0, s, 0, 0, 0);
      s = __builtin_amdgcn_mfma_f32_16x16x32_bf16(qf1, kf1, s, 0, 0, 0);
      int kvc = kvw0 + kvloc;
#pragma unroll
      for (int j = 0; j < 4; ++j) {
        int qr = q0 + si * 16 + g * 4 + j;
        bool valid = (kvc >= 0) && (kvc <= qr) && (kvc >= qr - WIN);
        float v = valid ? s[j] * 0.125f : -1e30f;
        s[j] = v;
        mx[j] = fmaxf(mx[j], v);
      }
      S[tt] = s;
    }
#pragma unroll
    for (int off = 1; off < 16; off <<= 1)
#pragma unroll
      for (int j = 0; j < 4; ++j) mx[j] = fmaxf(mx[j], __shfl_xor(mx[j], off, 64));
    float m[4], sum[4] = {0, 0, 0, 0};
#pragma unroll
    for (int j = 0; j < 4; ++j) m[j] = fmaxf(mx[j], snk);
#pragma unroll
    for (int tt = 0; tt < 9; ++tt)
#pragma unroll
      for (int j = 0; j < 4; ++j) {
        float p = (S[tt][j] > -1e29f) ? __expf(S[tt][j] - m[j]) : 0.0f;
        S[tt][j] = p;
        sum[j] += p;
      }
#pragma unroll
    for (int off = 1; off < 16; off <<= 1)
#pragma unroll
      for (int j = 0; j < 4; ++j) sum[j] += __shfl_xor(sum[j], off, 64);
    float rinv[4];
#pragma unroll
    for (int j = 0; j < 4; ++j) rinv[j] = 1.0f / (sum[j] + __expf(snk - m[j]));

    f32x4 acc[4] = {};
#pragma unroll
    for (int ks = 0; ks < 5; ++ks) {
#pragma unroll
      for (int c2 = 0; c2 < 2; ++c2) {
        int tt = 2 * ks + c2;
#pragma unroll
        for (int j = 0; j < 4; ++j) {
          float pv = (tt <= 8) ? S[tt][j] * rinv[j] : 0.0f;
          *(ushort*)(Pw + ((g * 4 + j) * 48 + c2 * 16 + r) * 2) = f2bf(pv);
        }
      }
      bf16x8 pa = *(const bf16x8*)(Pw + (r * 48 + g * 8) * 2);
#pragma unroll
      for (int ni = 0; ni < 4; ++ni) {
        int row = ni * 16 + r;
        int byte = (row * 320 + (si * 16 + ks * 32 + g * 8) * 2) ^ ((row & 7) << 4);
        bf16x8 vb = *(const bf16x8*)(lds + 20480 + byte);
        acc[ni] = __builtin_amdgcn_mfma_f32_16x16x32_bf16(pa, vb, acc[ni], 0, 0, 0);
      }
    }
#pragma unroll
    for (int ni = 0; ni < 4; ++ni)
#pragma unroll
      for (int j = 0; j < 4; ++j)
        out[(size_t)(q0 + si * 16 + g * 4 + j) * 4096 + h * 64 + ni * 16 + r] = f2bf(acc[ni][j]);
  }
}

extern "C" void kernel_launch(void* const* d_in, const int* in_sizes, int n_in,
                              void* d_out, int out_size, void* d_ws, size_t ws_size,
                              hipStream_t stream) {
  const float* hs = (const float*)d_in[0];
  const float* Wq = (const float*)d_in[1];
  const float* bq = (const float*)d_in[2];
  const float* Wk = (const float*)d_in[3];
  const float* bk = (const float*)d_in[4];
  const float* Wv = (const float*)d_in[5];
  const float* bv = (const float*)d_in[6];
  const float* Wo = (const float*)d_in[7];
  const float* bo = (const float*)d_in[8];
  const float* sinks = (const float*)d_in[9];
  float* out = (float*)d_out;

  char* ws = (char*)d_ws;
  ushort* hs_bf   = (ushort*)(ws + 0);            // 2048x2880 bf16      11,796,480 B
  ushort* vt_g    = (ushort*)(ws + 0);            // 512x2048  bf16 (reuses hs_bf after QKV GEMM)
  ushort* wqkv_t  = (ushort*)(ws + 11796480);     // 5120x2880 bf16      29,491,200 B
  ushort* attn    = (ushort*)(ws + 11796480);     // 2048x4096 bf16 (reuses wqkv_t after QKV GEMM)
  ushort* wo_t    = (ushort*)(ws + 41287680);     // 2880x4096 bf16      23,592,960 B
  ushort* qkv     = (ushort*)(ws + 66453504);     // 2048x5120 bf16      20,971,520 B
  float*  bias_all= (float*)(ws + 87425024);      // 5120 f32
  float2* tab     = (float2*)(ws + 87445504);     // 2048x32 float2

  // prep: conversions / transposes / tables
  conv_kernel<<<5898240 / 4 / 256, 256, 0, stream>>>(hs, hs_bf, 5898240);
  tconv_kernel<<<dim3(4096 / 32, 2880 / 32), 256, 0, stream>>>(Wq, wqkv_t, 2880, 4096, 2880, 0);
  tconv_kernel<<<dim3(512 / 32, 2880 / 32), 256, 0, stream>>>(Wk, wqkv_t, 2880, 512, 2880, 4096);
  tconv_kernel<<<dim3(512 / 32, 2880 / 32), 256, 0, stream>>>(Wv, wqkv_t, 2880, 512, 2880, 4608);
  tconv_kernel<<<dim3(2880 / 32, 4096 / 32), 256, 0, stream>>>(Wo, wo_t, 4096, 2880, 4096, 0);
  biascat_kernel<<<20, 256, 0, stream>>>(bq, bk, bv, bias_all);
  ropetab_kernel<<<2048 * 32 / 256, 256, 0, stream>>>(tab);

  // QKV projection: [2048x2880] x [2880x5120] -> qkv (bf16, +bias). 16m x 16n = 256 wg
  gemm8_kernel<320, true><<<256, 512, 0, stream>>>(hs_bf, wqkv_t, bias_all, qkv,
                                                   2880, 2880, 2880, 5120);
  // RoPE in-place on Q and K regions
  rope_kernel<<<8388608 / 256, 256, 0, stream>>>(qkv, tab, 4096, 8388608);
  rope_kernel<<<1048576 / 256, 256, 0, stream>>>(qkv + 4096, tab, 512, 1048576);
  // V transpose (into dead hs_bf region)
  vt_kernel<<<dim3(32, 8), 256, 0, stream>>>(qkv, vt_g);
  // attention (into dead wqkv_t region)
  attn_kernel<<<dim3(64, 8), 512, 0, stream>>>(qkv, vt_g, sinks, attn);
  // output projection: [2048x4096] x [4096x2880] -> out (f32, +bo). 16m x 15n = 240 wg
  gemm8_kernel<192, false><<<240, 512, 0, stream>>>(attn, wo_t, bo, out,
                                                    4096, 4096, 4096, 2880);
}